// Round 7
// baseline (365.053 us; speedup 1.0000x reference)
//
#include <hip/hip_runtime.h>

#define NFEAT 256
#define GS 32
#define NG 8
#define BATCH 32
#define HW 4096
#define NTOT (BATCH*HW)   // 131072 samples per channel
#define EPSV 1e-5f

// ws layout (float offsets)
#define RPART_SZ (NG*64*1024)                 // 524288 floats
#define SPART_OFF (RPART_SZ)                  // 8*64*32 = 16384
#define WMT_OFF   (SPART_OFF + NG*64*32)      // 8*1024
#define BETA_OFF  (WMT_OFF + NG*1024)         // 8*32

// ---------------------------------------------------------------------------
// Kernel 1: per-(g,b,half) partial raw gram R = X X^T and channel sums S.
// R7 CONFIRMED the unified spill theory (R1/R4/R5/R6): __launch_bounds__
// min-waves arg sets the VGPR cap; (1024,1) + unroll-4 on the s-loop ->
// VGPR=40, WRITE 2.59GB->2.1MB, 923->84us, VALUBusy 62%. DO NOT TOUCH:
// this kernel is the control this round. (Remaining headroom: ~38us of
// VALU is LDS addressing overhead; possible later lever, not now.)
// ---------------------------------------------------------------------------
__global__ __launch_bounds__(1024, 1) void dbn_stats(const float* __restrict__ x,
                                                     float* __restrict__ Rpart,
                                                     float* __restrict__ Spart) {
    __shared__ float buf[2][32][260];   // 66.6 KB
    __shared__ float sscr[4][32];       // channel-sum partials per sp

    int bx = blockIdx.x;            // 0..511
    int g  = bx >> 6;
    int pb = bx & 63;               // b*2 + h
    int b  = pb >> 1, h = pb & 1;
    int tid = threadIdx.x;
    int w  = tid >> 6;              // wave 0..15
    int l  = tid & 63;
    int sp = w >> 2;                // sample slice 0..3 (64 samples of chunk)
    int t  = w & 3;                 // tile id: (tr1, tc1) in 2x2 grid of 16x16
    int tr1 = t >> 1, tc1 = t & 1;
    int li = l >> 3, lj = l & 7;    // lane 8x8 grid; lane owns 2x2 entries

    const float* xg = x + ((size_t)(b*NFEAT + g*GS))*HW + h*2048;

    int r0 = w*2, r1 = w*2 + 1;     // rows this wave stages each chunk
    int rrow = tr1*16 + 2*li;       // gram rows rrow, rrow+1
    int crow = tc1*16 + 2*lj;       // gram cols crow, crow+1

    float acc00 = 0.f, acc01 = 0.f, acc10 = 0.f, acc11 = 0.f;
    float srow0 = 0.f, srow1 = 0.f;

    // stage chunk 0 into buf[0]
    {
        float4 st0 = *(const float4*)(xg + (size_t)r0*HW + l*4);
        float4 st1 = *(const float4*)(xg + (size_t)r1*HW + l*4);
        *(float4*)&buf[0][r0][l*4] = st0;
        *(float4*)&buf[0][r1][l*4] = st1;
    }

    #pragma unroll 1
    for (int ck = 0; ck < 8; ++ck) {
        __syncthreads();   // staged data visible + prev compute done
        int cur = ck & 1, bb = cur ^ 1;
        float4 st0, st1;
        bool pf = (ck < 7);
        if (pf) {          // issue next chunk's loads NOW; drain after compute
            st0 = *(const float4*)(xg + (size_t)r0*HW + (ck+1)*256 + l*4);
            st1 = *(const float4*)(xg + (size_t)r1*HW + (ck+1)*256 + l*4);
        }
        int soff = sp*64;
        #pragma unroll 4
        for (int s = 0; s < 16; ++s) {
            int sa = soff + s*4;
            float4 ra0 = *(const float4*)&buf[cur][rrow    ][sa];
            float4 ra1 = *(const float4*)&buf[cur][rrow + 1][sa];
            float4 cb0 = *(const float4*)&buf[cur][crow    ][sa];
            float4 cb1 = *(const float4*)&buf[cur][crow + 1][sa];
            acc00 = fmaf(ra0.x, cb0.x, acc00); acc00 = fmaf(ra0.y, cb0.y, acc00);
            acc00 = fmaf(ra0.z, cb0.z, acc00); acc00 = fmaf(ra0.w, cb0.w, acc00);
            acc01 = fmaf(ra0.x, cb1.x, acc01); acc01 = fmaf(ra0.y, cb1.y, acc01);
            acc01 = fmaf(ra0.z, cb1.z, acc01); acc01 = fmaf(ra0.w, cb1.w, acc01);
            acc10 = fmaf(ra1.x, cb0.x, acc10); acc10 = fmaf(ra1.y, cb0.y, acc10);
            acc10 = fmaf(ra1.z, cb0.z, acc10); acc10 = fmaf(ra1.w, cb0.w, acc10);
            acc11 = fmaf(ra1.x, cb1.x, acc11); acc11 = fmaf(ra1.y, cb1.y, acc11);
            acc11 = fmaf(ra1.z, cb1.z, acc11); acc11 = fmaf(ra1.w, cb1.w, acc11);
            if (tc1 == 0) {   // wave-uniform branch; tc1==0 waves own row sums
                srow0 += (ra0.x + ra0.y) + (ra0.z + ra0.w);
                srow1 += (ra1.x + ra1.y) + (ra1.z + ra1.w);
            }
        }
        if (pf) {          // vmcnt(0) lands here, after ~1000cy of compute
            *(float4*)&buf[bb][r0][l*4] = st0;
            *(float4*)&buf[bb][r1][l*4] = st1;
        }
    }

    __syncthreads();   // all compute done; safe to overlay scratch on buf

    // sp-reduction scratch: [sp*4+t][lane][4 entries] = 16 KB inside buf
    float* scr = &buf[0][0][0];
    scr[((sp*4 + t)*64 + l)*4 + 0] = acc00;
    scr[((sp*4 + t)*64 + l)*4 + 1] = acc01;
    scr[((sp*4 + t)*64 + l)*4 + 2] = acc10;
    scr[((sp*4 + t)*64 + l)*4 + 3] = acc11;
    if (tc1 == 0 && lj == 0) {
        sscr[sp][tr1*16 + 2*li + 0] = srow0;
        sscr[sp][tr1*16 + 2*li + 1] = srow1;
    }
    __syncthreads();

    // 1024 threads <-> 1024 gram entries: sum the 4 sp-slices, store.
    {
        int tt = tid >> 8;            // tile 0..3
        int ll = (tid >> 2) & 63;     // lane slot
        int e  = tid & 3;             // entry 0..3 (rr*2+cc)
        float s = scr[((0*4 + tt)*64 + ll)*4 + e]
                + scr[((1*4 + tt)*64 + ll)*4 + e]
                + scr[((2*4 + tt)*64 + ll)*4 + e]
                + scr[((3*4 + tt)*64 + ll)*4 + e];
        int ttr = tt >> 1, ttc = tt & 1;
        int lli = ll >> 3, llj = ll & 7;
        int row = ttr*16 + 2*lli + (e >> 1);
        int col = ttc*16 + 2*llj + (e & 1);
        Rpart[(size_t)(g*64 + pb)*1024 + row*32 + col] = s;
    }
    if (tid < 32) {
        float s = sscr[0][tid] + sscr[1][tid] + sscr[2][tid] + sscr[3][tid];
        Spart[(size_t)(g*64 + pb)*32 + tid] = s;
    }
}

// ---------------------------------------------------------------------------
// Kernel 2: per-group solver — EXACT round-1 version, unchanged (control).
// Estimated ~20us from first principles; if next round's total doesn't move
// with the whiten fix, solver (or in-graph ws re-poison) is the residual.
// ---------------------------------------------------------------------------
__global__ __launch_bounds__(1024) void dbn_solver(const float* __restrict__ Rpart, const float* __restrict__ Spart,
                           const float* __restrict__ weight, const float* __restrict__ bias,
                           float* __restrict__ wmT, float* __restrict__ beta) {
    __shared__ float Y[1024], Z[1024], T[1024], S[32], M[32];
    __shared__ float sh_s;
    int g = blockIdx.x;
    int tid = threadIdx.x;
    int c = tid >> 5, d = tid & 31;

    if (tid < 32) {
        float s = 0.f;
        #pragma unroll 4
        for (int pb = 0; pb < 64; ++pb) s += Spart[(size_t)(g*64 + pb)*32 + tid];
        S[tid] = s;
        M[tid] = s / (float)NTOT;
    }
    float rs = 0.f;
    #pragma unroll 4
    for (int pb = 0; pb < 64; ++pb) rs += Rpart[(size_t)(g*64 + pb)*1024 + tid];
    __syncthreads();

    const float invN = 1.0f/(float)NTOT;
    float v = rs - S[c]*S[d]*invN;
    if (c == d) v += EPSV;
    T[tid] = v;
    __syncthreads();

    if (tid == 0) {
        float tr = 0.f;
        for (int k = 0; k < 32; ++k) tr += T[k*33];
        sh_s = tr / 32.0f;
    }
    __syncthreads();
    float sc = sh_s;
    float invs = 1.0f / sc;

    Y[tid] = v * invs;
    Z[tid] = (c == d) ? 1.0f : 0.0f;
    __syncthreads();

    for (int it = 0; it < 8; ++it) {
        float s2 = 0.f;
        #pragma unroll
        for (int k = 0; k < 32; ++k) s2 = fmaf(Z[c*32 + k], Y[k*32 + d], s2);
        float a = ((c == d) ? 3.0f : 0.0f) - s2;
        __syncthreads();
        T[tid] = a;
        __syncthreads();
        float sy = 0.f, sz = 0.f;
        #pragma unroll
        for (int k = 0; k < 32; ++k) {
            sy = fmaf(Y[c*32 + k], T[k*32 + d], sy);
            sz = fmaf(T[c*32 + k], Z[k*32 + d], sz);
        }
        __syncthreads();
        Y[tid] = 0.5f*sy;
        Z[tid] = 0.5f*sz;
        __syncthreads();
    }

    float wfac = rsqrtf(sc);   // sigma^{-1/2} = Z / sqrt(s)
    wmT[(size_t)g*1024 + d*32 + c] = Z[tid]*wfac*weight[g*GS + c];  // transposed + weight-folded
    if (tid < 32) {
        float s2 = 0.f;
        #pragma unroll
        for (int k = 0; k < 32; ++k) s2 = fmaf(Z[tid*32 + k], M[k], s2);
        beta[g*GS + tid] = -s2*wfac*weight[g*GS + tid] + bias[g*GS + tid];
    }
}

// ---------------------------------------------------------------------------
// Kernel 3: whiten — R8 rewrite, spill-proof by construction.
// Old version held v[32]+acc[32] = 64 live floats at default launch_bounds ->
// the exact register-cliff pattern proven in stats (R1/R4/R5/R6). New layout:
// thread = 2 samples x 16 channels (channel-split):
//   acc = 16 float2 = 32 VGPR; x[d] streamed as float2 (8B/lane -> 512B
//   per wave-load AND wave-store); wmT/beta indices wave-uniform -> s_load.
//   ~46 VGPR total -> 8 waves/SIMD, no cliff. Both channel-halves read the
//   same x rows; dedupes in L1/L2, HBM unique bytes unchanged (268 MB).
// Accumulation order over d unchanged -> identical numerics.
// unroll 4 on d-loop: 4 float2 loads in flight (static acc indices only).
// ---------------------------------------------------------------------------
__global__ __launch_bounds__(256, 4) void dbn_whiten(const float* __restrict__ x,
                                                     const float* __restrict__ wmT,
                                                     const float* __restrict__ beta,
                                                     float* __restrict__ out) {
    int bx = blockIdx.x;            // 0..4095
    int gb = bx >> 4;               // 0..255
    int chunk = bx & 15;            // 256-sample chunk
    int b = gb >> 3, g = gb & 7;
    int tid = threadIdx.x;
    int hc = tid >> 7;              // channel half 0/1 (16 channels)
    int s  = tid & 127;             // sample pair index (2 samples)

    size_t sbase = ((size_t)(b*NFEAT + g*GS))*HW + chunk*256 + 2*s;
    const float* wg = wmT + (size_t)g*1024 + hc*16;   // wg[d*32 + c]
    const float* bg = beta + (size_t)g*GS + hc*16;

    float2 acc[16];
    #pragma unroll
    for (int c = 0; c < 16; ++c) { float bc = bg[c]; acc[c].x = bc; acc[c].y = bc; }

    #pragma unroll 4
    for (int d = 0; d < 32; ++d) {
        float2 vd = *(const float2*)(x + sbase + (size_t)d*HW);
        #pragma unroll
        for (int c = 0; c < 16; ++c) {
            float wv = wg[d*32 + c];
            acc[c].x = fmaf(wv, vd.x, acc[c].x);
            acc[c].y = fmaf(wv, vd.y, acc[c].y);
        }
    }

    size_t obase = ((size_t)(b*NFEAT + g*GS + hc*16))*HW + chunk*256 + 2*s;
    #pragma unroll
    for (int c = 0; c < 16; ++c)
        *(float2*)(out + obase + (size_t)c*HW) = acc[c];
}

extern "C" void kernel_launch(void* const* d_in, const int* in_sizes, int n_in,
                              void* d_out, int out_size, void* d_ws, size_t ws_size,
                              hipStream_t stream) {
    const float* x      = (const float*)d_in[0];
    const float* weight = (const float*)d_in[1];
    const float* bias   = (const float*)d_in[2];
    float* out = (float*)d_out;
    float* ws  = (float*)d_ws;

    float* Rpart = ws;
    float* Spart = ws + SPART_OFF;
    float* wmT   = ws + WMT_OFF;
    float* beta  = ws + BETA_OFF;

    dbn_stats <<<512, 1024, 0, stream>>>(x, Rpart, Spart);
    dbn_solver<<<NG, 1024, 0, stream>>>(Rpart, Spart, weight, bias, wmT, beta);
    dbn_whiten<<<4096, 256, 0, stream>>>(x, wmT, beta, out);
}

// Round 8
// 308.414 us; speedup vs baseline: 1.1836x; 1.1836x over previous
//
#include <hip/hip_runtime.h>

#define NFEAT 256
#define GS 32
#define NG 8
#define BATCH 32
#define HW 4096
#define NTOT (BATCH*HW)   // 131072 samples per channel
#define EPSV 1e-5f

// ws layout (float offsets)
#define RPART_SZ (NG*64*1024)                 // 524288 floats
#define SPART_OFF (RPART_SZ)                  // 8*64*32 = 16384
#define WMT_OFF   (SPART_OFF + NG*64*32)      // 8*1024
#define BETA_OFF  (WMT_OFF + NG*1024)         // 8*32

// ---------------------------------------------------------------------------
// Kernel 1: per-(g,b,half) partial raw gram R = X X^T and channel sums S.
// R7 proved the schedule (reg-staged dense loads, vmcnt-after-compute, LDS
// dbuf, (1024,1) spill-fix): 84us, VALUBusy 62%, 0 conflicts, WRITE 2.1MB.
// R8 analysis: 62% x 84us = 52us VALU issue vs 13.7us pure-FMA floor -> the
// 2x2/lane tile wastes ~3x VALU (4 ds_read per 16 FMA + addressing + srow).
// R9 (tile shape ONLY; staging/barriers byte-identical):
//  - 16 waves = 16 sample-slices; each wave computes the FULL 32x32 gram for
//    its 16 samples/chunk. Lane (li,lj) owns the stride-8 tile rows {li+8i}
//    x cols {lj+8j}: per step 8 ds_read_b128 -> 64 FMA (1:8, was 1:4).
//  - Stride-8 is the conflict-free choice: per instruction lanes read
//    consecutive rows -> dAddr = 260 ? 4 mod 32 -> quads {0,4..28} = all 32
//    banks. (A 4li tile would be 4-way conflicted.)
//  - srow wave-uniform (divergent tc1 branch gone).
//  - acc16 + ra/cb32 + st8 ~ 70 VGPR; unroll 1 on the 4-step s-loop.
// ---------------------------------------------------------------------------
__global__ __launch_bounds__(1024, 1) void dbn_stats(const float* __restrict__ x,
                                                     float* __restrict__ Rpart,
                                                     float* __restrict__ Spart) {
    __shared__ float buf[2][32][260];   // 66.6 KB; row stride 260 = 4 mod 32
    __shared__ float sscr[16][32];      // channel-sum partials per wave

    int bx = blockIdx.x;            // 0..511
    int g  = bx >> 6;
    int pb = bx & 63;               // b*2 + h
    int b  = pb >> 1, h = pb & 1;
    int tid = threadIdx.x;
    int w  = tid >> 6;              // wave 0..15 = sample slice (16 samples/chunk)
    int l  = tid & 63;
    int li = l >> 3, lj = l & 7;    // lane 8x8 grid; stride-8 4x4 tile

    const float* xg = x + ((size_t)(b*NFEAT + g*GS))*HW + h*2048;

    int r0 = w*2, r1 = w*2 + 1;     // rows this wave stages each chunk

    float acc[4][4];
    float srow[4];
    #pragma unroll
    for (int i = 0; i < 4; ++i) {
        srow[i] = 0.f;
        #pragma unroll
        for (int j = 0; j < 4; ++j) acc[i][j] = 0.f;
    }

    // stage chunk 0 into buf[0]
    {
        float4 st0 = *(const float4*)(xg + (size_t)r0*HW + l*4);
        float4 st1 = *(const float4*)(xg + (size_t)r1*HW + l*4);
        *(float4*)&buf[0][r0][l*4] = st0;
        *(float4*)&buf[0][r1][l*4] = st1;
    }

    #pragma unroll 1
    for (int ck = 0; ck < 8; ++ck) {
        __syncthreads();   // staged data visible + prev compute done
        int cur = ck & 1, bb = cur ^ 1;
        float4 st0, st1;
        bool pf = (ck < 7);
        if (pf) {          // issue next chunk's loads NOW; drain after compute
            st0 = *(const float4*)(xg + (size_t)r0*HW + (ck+1)*256 + l*4);
            st1 = *(const float4*)(xg + (size_t)r1*HW + (ck+1)*256 + l*4);
        }
        #pragma unroll 1
        for (int s = 0; s < 4; ++s) {
            int sa = w*16 + s*4;    // this wave's samples, 4 per step
            float4 ra[4], cb[4];
            #pragma unroll
            for (int i = 0; i < 4; ++i)
                ra[i] = *(const float4*)&buf[cur][li + 8*i][sa];
            #pragma unroll
            for (int j = 0; j < 4; ++j)
                cb[j] = *(const float4*)&buf[cur][lj + 8*j][sa];
            #pragma unroll
            for (int i = 0; i < 4; ++i) {
                #pragma unroll
                for (int j = 0; j < 4; ++j) {
                    float a = acc[i][j];
                    a = fmaf(ra[i].x, cb[j].x, a);
                    a = fmaf(ra[i].y, cb[j].y, a);
                    a = fmaf(ra[i].z, cb[j].z, a);
                    a = fmaf(ra[i].w, cb[j].w, a);
                    acc[i][j] = a;
                }
                srow[i] += (ra[i].x + ra[i].y) + (ra[i].z + ra[i].w);
            }
        }
        if (pf) {          // vmcnt(0) lands here, after the compute phase
            *(float4*)&buf[bb][r0][l*4] = st0;
            *(float4*)&buf[bb][r1][l*4] = st1;
        }
    }

    __syncthreads();   // all compute done; safe to overlay scratch on buf

    // slot-major scr overlay: scr[slot*1024 + w*64 + l], slot = i*4+j.
    // Writes per slot: consecutive lanes -> conflict-free. 16K floats <= buf.
    float* scr = &buf[0][0][0];
    #pragma unroll
    for (int i = 0; i < 4; ++i)
        #pragma unroll
        for (int j = 0; j < 4; ++j)
            scr[(i*4 + j)*1024 + w*64 + l] = acc[i][j];
    if (lj == 0) {
        #pragma unroll
        for (int i = 0; i < 4; ++i) sscr[w][li + 8*i] = srow[i];
    }
    __syncthreads();

    // 1024 threads <-> 1024 gram entries: sum the 16 wave-slices, store.
    {
        int r = tid >> 5, c = tid & 31;
        int lane = (r & 7)*8 + (c & 7);
        int slot = (r >> 3)*4 + (c >> 3);
        float s = 0.f;
        #pragma unroll
        for (int ww = 0; ww < 16; ++ww) s += scr[slot*1024 + ww*64 + lane];
        Rpart[(size_t)(g*64 + pb)*1024 + tid] = s;
    }
    if (tid < 32) {
        float s = 0.f;
        #pragma unroll
        for (int ww = 0; ww < 16; ++ww) s += sscr[ww][tid];
        Spart[(size_t)(g*64 + pb)*32 + tid] = s;
    }
}

// ---------------------------------------------------------------------------
// Kernel 2: per-group solver — EXACT round-1 version, unchanged (control).
// ---------------------------------------------------------------------------
__global__ __launch_bounds__(1024) void dbn_solver(const float* __restrict__ Rpart, const float* __restrict__ Spart,
                           const float* __restrict__ weight, const float* __restrict__ bias,
                           float* __restrict__ wmT, float* __restrict__ beta) {
    __shared__ float Y[1024], Z[1024], T[1024], S[32], M[32];
    __shared__ float sh_s;
    int g = blockIdx.x;
    int tid = threadIdx.x;
    int c = tid >> 5, d = tid & 31;

    if (tid < 32) {
        float s = 0.f;
        #pragma unroll 4
        for (int pb = 0; pb < 64; ++pb) s += Spart[(size_t)(g*64 + pb)*32 + tid];
        S[tid] = s;
        M[tid] = s / (float)NTOT;
    }
    float rs = 0.f;
    #pragma unroll 4
    for (int pb = 0; pb < 64; ++pb) rs += Rpart[(size_t)(g*64 + pb)*1024 + tid];
    __syncthreads();

    const float invN = 1.0f/(float)NTOT;
    float v = rs - S[c]*S[d]*invN;
    if (c == d) v += EPSV;
    T[tid] = v;
    __syncthreads();

    if (tid == 0) {
        float tr = 0.f;
        for (int k = 0; k < 32; ++k) tr += T[k*33];
        sh_s = tr / 32.0f;
    }
    __syncthreads();
    float sc = sh_s;
    float invs = 1.0f / sc;

    Y[tid] = v * invs;
    Z[tid] = (c == d) ? 1.0f : 0.0f;
    __syncthreads();

    for (int it = 0; it < 8; ++it) {
        float s2 = 0.f;
        #pragma unroll
        for (int k = 0; k < 32; ++k) s2 = fmaf(Z[c*32 + k], Y[k*32 + d], s2);
        float a = ((c == d) ? 3.0f : 0.0f) - s2;
        __syncthreads();
        T[tid] = a;
        __syncthreads();
        float sy = 0.f, sz = 0.f;
        #pragma unroll
        for (int k = 0; k < 32; ++k) {
            sy = fmaf(Y[c*32 + k], T[k*32 + d], sy);
            sz = fmaf(T[c*32 + k], Z[k*32 + d], sz);
        }
        __syncthreads();
        Y[tid] = 0.5f*sy;
        Z[tid] = 0.5f*sz;
        __syncthreads();
    }

    float wfac = rsqrtf(sc);   // sigma^{-1/2} = Z / sqrt(s)
    wmT[(size_t)g*1024 + d*32 + c] = Z[tid]*wfac*weight[g*GS + c];  // transposed + weight-folded
    if (tid < 32) {
        float s2 = 0.f;
        #pragma unroll
        for (int k = 0; k < 32; ++k) s2 = fmaf(Z[tid*32 + k], M[k], s2);
        beta[g*GS + tid] = -s2*wfac*weight[g*GS + tid] + bias[g*GS + tid];
    }
}

// ---------------------------------------------------------------------------
// Kernel 3: whiten — EXACT round-1 version, REVERTED. R8's channel-split
// float2 rewrite regressed ~54 -> 96us (latency-bound, 2x load issue from
// both halves re-reading every x row). R1 version is ~54us = 79% of its
// 43us memory floor — acceptable; do not touch without a better theory.
// ---------------------------------------------------------------------------
__global__ __launch_bounds__(256) void dbn_whiten(const float* __restrict__ x,
                                                  const float* __restrict__ wmT,
                                                  const float* __restrict__ beta,
                                                  float* __restrict__ out) {
    int bx = blockIdx.x;            // 0..4095
    int gb = bx >> 4;               // 0..255
    int chunk = bx & 15;
    int b = gb >> 3, g = gb & 7;
    size_t base = ((size_t)(b*NFEAT + g*GS))*HW + chunk*256 + threadIdx.x;
    const float* wg = wmT + (size_t)g*1024;
    const float* bg = beta + (size_t)g*GS;

    float v[32];
    #pragma unroll
    for (int d = 0; d < 32; ++d) v[d] = x[base + (size_t)d*HW];

    float acc[32];
    #pragma unroll
    for (int c = 0; c < 32; ++c) acc[c] = bg[c];

    #pragma unroll
    for (int d = 0; d < 32; ++d) {
        float vd = v[d];
        #pragma unroll
        for (int c = 0; c < 32; ++c) acc[c] = fmaf(wg[d*32 + c], vd, acc[c]);
    }

    #pragma unroll
    for (int c = 0; c < 32; ++c) out[base + (size_t)c*HW] = acc[c];
}

extern "C" void kernel_launch(void* const* d_in, const int* in_sizes, int n_in,
                              void* d_out, int out_size, void* d_ws, size_t ws_size,
                              hipStream_t stream) {
    const float* x      = (const float*)d_in[0];
    const float* weight = (const float*)d_in[1];
    const float* bias   = (const float*)d_in[2];
    float* out = (float*)d_out;
    float* ws  = (float*)d_ws;

    float* Rpart = ws;
    float* Spart = ws + SPART_OFF;
    float* wmT   = ws + WMT_OFF;
    float* beta  = ws + BETA_OFF;

    dbn_stats <<<512, 1024, 0, stream>>>(x, Rpart, Spart);
    dbn_solver<<<NG, 1024, 0, stream>>>(Rpart, Spart, weight, bias, wmT, beta);
    dbn_whiten<<<4096, 256, 0, stream>>>(x, wmT, beta, out);
}